// Round 10
// baseline (276.344 us; speedup 1.0000x reference)
//
#include <hip/hip_runtime.h>
#include <hip/hip_bf16.h>
#include <stdint.h>

// exp(s/sqrt(128)) = exp2(s * log2(e)/sqrt(128)); folded into Q at k_qk epilogue
#define SCALE_LOG2E 0.12751743f

typedef __bf16 bf16x8 __attribute__((ext_vector_type(8)));
typedef float floatx4 __attribute__((ext_vector_type(4)));
typedef uint32_t u32x4v __attribute__((ext_vector_type(4)));

__device__ __forceinline__ bf16x8 load_bf8(const void* p) {
    u32x4v v = *(const u32x4v*)p;
    return __builtin_bit_cast(bf16x8, v);
}

__device__ __forceinline__ bf16x8 cvt8(float4 u, float4 v) {
    union { bf16x8 v8; __hip_bfloat16 h[8]; } r;
    r.h[0] = __float2bfloat16(u.x); r.h[1] = __float2bfloat16(u.y);
    r.h[2] = __float2bfloat16(u.z); r.h[3] = __float2bfloat16(u.w);
    r.h[4] = __float2bfloat16(v.x); r.h[5] = __float2bfloat16(v.y);
    r.h[6] = __float2bfloat16(v.z); r.h[7] = __float2bfloat16(v.w);
    return r.v8;
}

// async 16B global -> LDS DMA (no VGPR destination; compiler cannot collapse)
__device__ __forceinline__ void dma16(const void* g, void* l) {
    __builtin_amdgcn_global_load_lds(
        (const __attribute__((address_space(1))) uint32_t*)g,
        (__attribute__((address_space(3))) uint32_t*)l, 16, 0, 0);
}

// ---------------------------------------------------------------------------
// Kernel A: cvt w_q,w_k -> bf16 (b<96); c[768] = w_o @ w_v (b 96..98);
// zero num/den (b 99..131; num_g/den_g contiguous 16384 floats in ws).
// (byte-identical to round-9 / 146.4 us anchor)
// ---------------------------------------------------------------------------
__global__ void k_prep(const float* __restrict__ w_q, const float* __restrict__ w_k,
                       const float* __restrict__ w_v, const float* __restrict__ w_o,
                       __hip_bfloat16* __restrict__ wq_bf,
                       __hip_bfloat16* __restrict__ wk_bf,
                       float* __restrict__ c_out,
                       float* __restrict__ numden) {
    int b = blockIdx.x;
    int t = threadIdx.x;
    if (b < 96) {
        #pragma unroll
        for (int p = 0; p < 8; ++p) {
            int i = b * 2048 + p * 256 + t;
            if (i < 98304) wq_bf[i] = __float2bfloat16(w_q[i]);
            else           wk_bf[i - 98304] = __float2bfloat16(w_k[i - 98304]);
        }
    } else if (b < 99) {
        int j = (b - 96) * 256 + t;
        float acc = 0.f;
        #pragma unroll 8
        for (int k = 0; k < 64; ++k) acc += w_o[k] * w_v[k * 768 + j];
        c_out[j] = acc;
    } else {
        int z = (b - 99) * 512 + t * 2;
        if (z < 16384) { numden[z] = 0.f; numden[z + 1] = 0.f; }
    }
}

// ---------------------------------------------------------------------------
// Kernel B: Q = x1 @ w_q^T * SCALE (bid 0..255), K = x2 @ w_k^T (256..511).
// vs = x2 . c fused into the K blocks. m97-style: 32 rows x 128 cols, BK=128,
// 6 K-iters, A-tile double-buffered via global_load_lds w=16, XOR-swizzled
// (c^(r&7)) at the global source. (byte-identical to round-9 anchor)
// ---------------------------------------------------------------------------
__global__ __launch_bounds__(256, 4) void k_qk(
        const float* __restrict__ x1, const float* __restrict__ x2,
        const __hip_bfloat16* __restrict__ wq_bf,
        const __hip_bfloat16* __restrict__ wk_bf,
        const float* __restrict__ c_in,
        __hip_bfloat16* __restrict__ Qb, __hip_bfloat16* __restrict__ Kb,
        float* __restrict__ vs_g) {
    __shared__ alignas(16) float sA[2][32 * 128];  // 2 x 16 KB, swizzled 16B chunks

    int bid = blockIdx.x;
    int t = threadIdx.x;

    bool isK = bid >= 256;
    int row0 = (bid & 255) * 32;
    const float* x = isK ? x2 : x1;
    const __hip_bfloat16* w = isK ? wk_bf : wq_bf;
    __hip_bfloat16* outp = isK ? Kb : Qb;

    int wave = t >> 6, lane = t & 63;
    int m = lane & 15, quad = lane >> 4;
    int col0 = wave * 32;

    const float* gsrc[4];
    #pragma unroll
    for (int p = 0; p < 4; ++p) {
        int s = wave * 256 + p * 64 + lane;
        int r = s >> 5, pos = s & 31;
        int c = pos ^ (r & 7);
        gsrc[p] = x + (size_t)(row0 + r) * 768 + c * 4;
    }
    auto dma_tile = [&](int buf, int kc) {
        #pragma unroll
        for (int p = 0; p < 4; ++p)
            dma16(gsrc[p] + kc, &sA[buf][(wave * 256 + p * 64) * 4]);
    };

    const __hip_bfloat16* bp = w + (size_t)(col0 + m) * 768 + quad * 8;

    floatx4 acc[2][2];
    #pragma unroll
    for (int i = 0; i < 2; ++i)
        #pragma unroll
        for (int j = 0; j < 2; ++j) acc[i][j] = {0.f, 0.f, 0.f, 0.f};

    float vacc = 0.f;
    int vr = t >> 3, vh = t & 7;

    dma_tile(0, 0);

    for (int it = 0; it < 6; ++it) {
        __syncthreads();            // drains all DMAs (incl. tile it); frees buf (it+1)&1
        if (it < 5) dma_tile((it + 1) & 1, (it + 1) * 128);

        const float* A = sA[it & 1];
        int kc = it * 128;
        #pragma unroll
        for (int ks = 0; ks < 4; ++ks) {
            bf16x8 afr[2], bfr[2];
            #pragma unroll
            for (int i = 0; i < 2; ++i) {
                int r = i * 16 + m;
                int cb = ks * 8 + quad * 2;
                int p0 = cb ^ (r & 7), p1 = (cb + 1) ^ (r & 7);
                float4 f0 = *(const float4*)&A[r * 128 + p0 * 4];
                float4 f1 = *(const float4*)&A[r * 128 + p1 * 4];
                afr[i] = cvt8(f0, f1);
            }
            #pragma unroll
            for (int j = 0; j < 2; ++j)
                bfr[j] = load_bf8(bp + (size_t)j * 16 * 768 + kc + ks * 32);
            #pragma unroll
            for (int i = 0; i < 2; ++i)
                #pragma unroll
                for (int j = 0; j < 2; ++j)
                    acc[i][j] = __builtin_amdgcn_mfma_f32_16x16x32_bf16(afr[i], bfr[j], acc[i][j], 0, 0, 0);
        }
        if (isK) {
            #pragma unroll
            for (int cc = 0; cc < 4; ++cc) {
                int c = vh * 4 + cc;
                int pos = c ^ (vr & 7);
                float4 av = *(const float4*)&A[vr * 128 + pos * 4];
                float4 cv = *(const float4*)&c_in[kc + c * 4];
                vacc += av.x * cv.x + av.y * cv.y + av.z * cv.z + av.w * cv.w;
            }
        }
    }

    float cscale = isK ? 1.0f : SCALE_LOG2E;
    #pragma unroll
    for (int i = 0; i < 2; ++i)
        #pragma unroll
        for (int j = 0; j < 2; ++j)
            #pragma unroll
            for (int r = 0; r < 4; ++r) {
                int row = row0 + i * 16 + quad * 4 + r;
                int col = col0 + j * 16 + m;
                outp[(size_t)row * 128 + col] = __float2bfloat16(acc[i][j][r] * cscale);
            }

    if (isK) {
        vacc += __shfl_xor(vacc, 1, 64);
        vacc += __shfl_xor(vacc, 2, 64);
        vacc += __shfl_xor(vacc, 4, 64);
        if (vh == 0) vs_g[row0 + vr] = vacc;
    }
}

// ---------------------------------------------------------------------------
// Kernel C: flash-style attention row-sums.
// ROUND-10 SINGLE CHANGE vs the 146.4 anchor: 512 threads = 8 waves/block
// (each wave owns 32 q-rows, qf[4][2]) instead of 4 waves x 64 q-rows.
// Same grid 512, same 68 KB LDS, same DMA double-buffer + 1 barrier/iter,
// same per-block work -- but 16 waves/CU = 4 waves/SIMD (vs 2), so one
// wave's MFMA overlaps another's ds_read/exp2 epilogue. VGPR per wave
// roughly halves (~110), under the 128 cap of __launch_bounds__(512,4).
// grid 512 = 64 q-blocks x 8 t-chunks. p = exp2(S) since Q pre-scaled.
// ---------------------------------------------------------------------------
__global__ __launch_bounds__(512, 4) void k_attn(
        const __hip_bfloat16* __restrict__ Qb, const __hip_bfloat16* __restrict__ Kb,
        const float* __restrict__ vs_g,
        float* __restrict__ num_g, float* __restrict__ den_g) {
    __shared__ alignas(16) __hip_bfloat16 sK[2][128 * 128];  // 2 x 32 KB, swizzled
    __shared__ float sVS[1024];

    int bid = blockIdx.x;
    int qb = bid >> 3, tc = bid & 7;
    int q0 = qb * 128, t0 = tc * 1024;

    int t = threadIdx.x;
    int wave = t >> 6, lane = t & 63;
    int wr = wave >> 1, wc = wave & 1;   // wr in [0,4): 32-q-row group; wc: t-col half
    int m = lane & 15, quad = lane >> 4;

    bf16x8 qf[4][2];
    #pragma unroll
    for (int i = 0; i < 2; ++i)
        #pragma unroll
        for (int kk = 0; kk < 4; ++kk)
            qf[kk][i] = load_bf8(Qb + (size_t)(q0 + wr * 32 + i * 16 + m) * 128 + kk * 32 + quad * 8);

    #pragma unroll
    for (int p = 0; p < 2; ++p) sVS[p * 512 + t] = vs_g[t0 + p * 512 + t];

    // DMA source mapping: tile = 128 rows x 16 chunks (16B), 2048 slots over
    // 512 threads. Slot s = p*512+t; r = s>>4, pos = s&15; chunk c = pos^(r&15).
    const __hip_bfloat16* gsrc[4];
    #pragma unroll
    for (int p = 0; p < 4; ++p) {
        int s = p * 512 + t;
        int r = s >> 4, pos = s & 15;
        int c = pos ^ (r & 15);
        gsrc[p] = Kb + (size_t)(t0 + r) * 128 + c * 8;
    }
    auto dma_tile = [&](int buf, int it) {
        #pragma unroll
        for (int p = 0; p < 4; ++p)
            dma16(gsrc[p] + (size_t)it * (128 * 128), &sK[buf][(p * 512 + wave * 64) * 8]);
    };

    float num_acc[2][4], den_acc[2][4];
    #pragma unroll
    for (int i = 0; i < 2; ++i)
        #pragma unroll
        for (int r = 0; r < 4; ++r) { num_acc[i][r] = 0.f; den_acc[i][r] = 0.f; }

    dma_tile(0, 0);

    for (int it = 0; it < 8; ++it) {
        __syncthreads();            // drains DMA tile it (+sVS on it=0); frees buf (it+1)&1
        if (it < 7) dma_tile((it + 1) & 1, it + 1);
        const __hip_bfloat16* K = sK[it & 1];

        #pragma unroll
        for (int j = 0; j < 4; ++j) {
            int row = wc * 64 + j * 16 + m;
            bf16x8 bfr[4];
            #pragma unroll
            for (int kk = 0; kk < 4; ++kk)
                bfr[kk] = load_bf8(&K[(size_t)row * 128 + (((kk * 4 + quad) ^ m) * 8)]);

            floatx4 acc[2];
            acc[0] = {0.f, 0.f, 0.f, 0.f};
            acc[1] = {0.f, 0.f, 0.f, 0.f};

            __builtin_amdgcn_s_setprio(1);
            #pragma unroll
            for (int kk = 0; kk < 4; ++kk)
                #pragma unroll
                for (int i = 0; i < 2; ++i)
                    acc[i] = __builtin_amdgcn_mfma_f32_16x16x32_bf16(qf[kk][i], bfr[kk], acc[i], 0, 0, 0);
            __builtin_amdgcn_s_setprio(0);

            float vsv = sVS[it * 128 + row];
            #pragma unroll
            for (int i = 0; i < 2; ++i)
                #pragma unroll
                for (int r = 0; r < 4; ++r) {
                    float p = __builtin_amdgcn_exp2f(acc[i][r]);
                    den_acc[i][r] += p;
                    num_acc[i][r] += p * vsv;
                }
        }
    }

    #pragma unroll
    for (int i = 0; i < 2; ++i)
        #pragma unroll
        for (int r = 0; r < 4; ++r) {
            float n = num_acc[i][r], d = den_acc[i][r];
            #pragma unroll
            for (int mask = 1; mask <= 8; mask <<= 1) {
                n += __shfl_xor(n, mask, 64);
                d += __shfl_xor(d, mask, 64);
            }
            if ((lane & 15) == 0) {
                int row = q0 + wr * 32 + i * 16 + quad * 4 + r;
                atomicAdd(&num_g[row], n);
                atomicAdd(&den_g[row], d);
            }
        }
}

// ---------------------------------------------------------------------------
// Kernel D: gated = x1 * (1 - num/den). float4 grid-mapped, memory-bound.
// (byte-identical to round-9 anchor)
// ---------------------------------------------------------------------------
__global__ void k_final(const float* __restrict__ x1,
                        const float* __restrict__ num_g,
                        const float* __restrict__ den_g,
                        float* __restrict__ outp) {
    int idx = blockIdx.x * 256 + threadIdx.x;  // float4 index, 192 per row
    int s = idx / 192;
    float4 v = *(const float4*)(x1 + (size_t)idx * 4);
    float g = 1.0f - num_g[s] / den_g[s];
    float4 rv;
    rv.x = v.x * g; rv.y = v.y * g; rv.z = v.z * g; rv.w = v.w * g;
    *(float4*)(outp + (size_t)idx * 4) = rv;
}

// ---------------------------------------------------------------------------
extern "C" void kernel_launch(void* const* d_in, const int* in_sizes, int n_in,
                              void* d_out, int out_size, void* d_ws, size_t ws_size,
                              hipStream_t stream) {
    const float* x1  = (const float*)d_in[0];
    const float* x2  = (const float*)d_in[1];
    const float* w_q = (const float*)d_in[2];
    const float* w_k = (const float*)d_in[3];
    const float* w_v = (const float*)d_in[4];
    const float* w_o = (const float*)d_in[5];
    float* outp = (float*)d_out;

    char* ws = (char*)d_ws;
    __hip_bfloat16* wq_bf = (__hip_bfloat16*)(ws + 0);        // 196608 B
    __hip_bfloat16* wk_bf = (__hip_bfloat16*)(ws + 196608);   // 196608 B
    float* c_buf          = (float*)(ws + 393216);            // 3072 B
    __hip_bfloat16* Qb    = (__hip_bfloat16*)(ws + 396288);   // 2 MB
    __hip_bfloat16* Kb    = (__hip_bfloat16*)(ws + 2493440);  // 2 MB
    float* vs_g           = (float*)(ws + 4590592);           // 32 KB
    float* num_g          = (float*)(ws + 4623360);           // 32 KB
    float* den_g          = (float*)(ws + 4656128);           // 32 KB (contig after num_g)

    k_prep<<<132, 256, 0, stream>>>(w_q, w_k, w_v, w_o, wq_bf, wk_bf, c_buf, num_g);
    k_qk<<<512, 256, 0, stream>>>(x1, x2, wq_bf, wk_bf, c_buf, Qb, Kb, vs_g);
    k_attn<<<512, 512, 0, stream>>>(Qb, Kb, vs_g, num_g, den_g);
    k_final<<<6144, 256, 0, stream>>>(x1, num_g, den_g, outp);
}

// Round 11
// 169.223 us; speedup vs baseline: 1.6330x; 1.6330x over previous
//
#include <hip/hip_runtime.h>
#include <hip/hip_bf16.h>
#include <stdint.h>

// exp(s/sqrt(128)) = exp2(s * log2(e)/sqrt(128)); folded into Q at k_qk epilogue
#define SCALE_LOG2E 0.12751743f

typedef __bf16 bf16x8 __attribute__((ext_vector_type(8)));
typedef float floatx4 __attribute__((ext_vector_type(4)));
typedef uint32_t u32x4v __attribute__((ext_vector_type(4)));

__device__ __forceinline__ bf16x8 load_bf8(const void* p) {
    u32x4v v = *(const u32x4v*)p;
    return __builtin_bit_cast(bf16x8, v);
}

__device__ __forceinline__ bf16x8 cvt8(float4 u, float4 v) {
    union { bf16x8 v8; __hip_bfloat16 h[8]; } r;
    r.h[0] = __float2bfloat16(u.x); r.h[1] = __float2bfloat16(u.y);
    r.h[2] = __float2bfloat16(u.z); r.h[3] = __float2bfloat16(u.w);
    r.h[4] = __float2bfloat16(v.x); r.h[5] = __float2bfloat16(v.y);
    r.h[6] = __float2bfloat16(v.z); r.h[7] = __float2bfloat16(v.w);
    return r.v8;
}

// async 16B global -> LDS DMA (no VGPR destination; compiler cannot collapse)
__device__ __forceinline__ void dma16(const void* g, void* l) {
    __builtin_amdgcn_global_load_lds(
        (const __attribute__((address_space(1))) uint32_t*)g,
        (__attribute__((address_space(3))) uint32_t*)l, 16, 0, 0);
}

// ---------------------------------------------------------------------------
// Kernel A: cvt w_q,w_k -> bf16 (b<96); c[768] = w_o @ w_v (b 96..98);
// zero num/den (b 99..131). (byte-identical to round-9 / 146.4 us anchor)
// ---------------------------------------------------------------------------
__global__ void k_prep(const float* __restrict__ w_q, const float* __restrict__ w_k,
                       const float* __restrict__ w_v, const float* __restrict__ w_o,
                       __hip_bfloat16* __restrict__ wq_bf,
                       __hip_bfloat16* __restrict__ wk_bf,
                       float* __restrict__ c_out,
                       float* __restrict__ numden) {
    int b = blockIdx.x;
    int t = threadIdx.x;
    if (b < 96) {
        #pragma unroll
        for (int p = 0; p < 8; ++p) {
            int i = b * 2048 + p * 256 + t;
            if (i < 98304) wq_bf[i] = __float2bfloat16(w_q[i]);
            else           wk_bf[i - 98304] = __float2bfloat16(w_k[i - 98304]);
        }
    } else if (b < 99) {
        int j = (b - 96) * 256 + t;
        float acc = 0.f;
        #pragma unroll 8
        for (int k = 0; k < 64; ++k) acc += w_o[k] * w_v[k * 768 + j];
        c_out[j] = acc;
    } else {
        int z = (b - 99) * 512 + t * 2;
        if (z < 16384) { numden[z] = 0.f; numden[z + 1] = 0.f; }
    }
}

// ---------------------------------------------------------------------------
// Kernel B: Q = x1 @ w_q^T * SCALE (bid 0..255), K = x2 @ w_k^T (256..511).
// vs = x2 . c fused into the K blocks. (byte-identical to round-9 anchor)
// ---------------------------------------------------------------------------
__global__ __launch_bounds__(256, 4) void k_qk(
        const float* __restrict__ x1, const float* __restrict__ x2,
        const __hip_bfloat16* __restrict__ wq_bf,
        const __hip_bfloat16* __restrict__ wk_bf,
        const float* __restrict__ c_in,
        __hip_bfloat16* __restrict__ Qb, __hip_bfloat16* __restrict__ Kb,
        float* __restrict__ vs_g) {
    __shared__ alignas(16) float sA[2][32 * 128];  // 2 x 16 KB, swizzled 16B chunks

    int bid = blockIdx.x;
    int t = threadIdx.x;

    bool isK = bid >= 256;
    int row0 = (bid & 255) * 32;
    const float* x = isK ? x2 : x1;
    const __hip_bfloat16* w = isK ? wk_bf : wq_bf;
    __hip_bfloat16* outp = isK ? Kb : Qb;

    int wave = t >> 6, lane = t & 63;
    int m = lane & 15, quad = lane >> 4;
    int col0 = wave * 32;

    const float* gsrc[4];
    #pragma unroll
    for (int p = 0; p < 4; ++p) {
        int s = wave * 256 + p * 64 + lane;
        int r = s >> 5, pos = s & 31;
        int c = pos ^ (r & 7);
        gsrc[p] = x + (size_t)(row0 + r) * 768 + c * 4;
    }
    auto dma_tile = [&](int buf, int kc) {
        #pragma unroll
        for (int p = 0; p < 4; ++p)
            dma16(gsrc[p] + kc, &sA[buf][(wave * 256 + p * 64) * 4]);
    };

    const __hip_bfloat16* bp = w + (size_t)(col0 + m) * 768 + quad * 8;

    floatx4 acc[2][2];
    #pragma unroll
    for (int i = 0; i < 2; ++i)
        #pragma unroll
        for (int j = 0; j < 2; ++j) acc[i][j] = {0.f, 0.f, 0.f, 0.f};

    float vacc = 0.f;
    int vr = t >> 3, vh = t & 7;

    dma_tile(0, 0);

    for (int it = 0; it < 6; ++it) {
        __syncthreads();            // drains all DMAs (incl. tile it); frees buf (it+1)&1
        if (it < 5) dma_tile((it + 1) & 1, (it + 1) * 128);

        const float* A = sA[it & 1];
        int kc = it * 128;
        #pragma unroll
        for (int ks = 0; ks < 4; ++ks) {
            bf16x8 afr[2], bfr[2];
            #pragma unroll
            for (int i = 0; i < 2; ++i) {
                int r = i * 16 + m;
                int cb = ks * 8 + quad * 2;
                int p0 = cb ^ (r & 7), p1 = (cb + 1) ^ (r & 7);
                float4 f0 = *(const float4*)&A[r * 128 + p0 * 4];
                float4 f1 = *(const float4*)&A[r * 128 + p1 * 4];
                afr[i] = cvt8(f0, f1);
            }
            #pragma unroll
            for (int j = 0; j < 2; ++j)
                bfr[j] = load_bf8(bp + (size_t)j * 16 * 768 + kc + ks * 32);
            #pragma unroll
            for (int i = 0; i < 2; ++i)
                #pragma unroll
                for (int j = 0; j < 2; ++j)
                    acc[i][j] = __builtin_amdgcn_mfma_f32_16x16x32_bf16(afr[i], bfr[j], acc[i][j], 0, 0, 0);
        }
        if (isK) {
            #pragma unroll
            for (int cc = 0; cc < 4; ++cc) {
                int c = vh * 4 + cc;
                int pos = c ^ (vr & 7);
                float4 av = *(const float4*)&A[vr * 128 + pos * 4];
                float4 cv = *(const float4*)&c_in[kc + c * 4];
                vacc += av.x * cv.x + av.y * cv.y + av.z * cv.z + av.w * cv.w;
            }
        }
    }

    float cscale = isK ? 1.0f : SCALE_LOG2E;
    #pragma unroll
    for (int i = 0; i < 2; ++i)
        #pragma unroll
        for (int j = 0; j < 2; ++j)
            #pragma unroll
            for (int r = 0; r < 4; ++r) {
                int row = row0 + i * 16 + quad * 4 + r;
                int col = col0 + j * 16 + m;
                outp[(size_t)row * 128 + col] = __float2bfloat16(acc[i][j][r] * cscale);
            }

    if (isK) {
        vacc += __shfl_xor(vacc, 1, 64);
        vacc += __shfl_xor(vacc, 2, 64);
        vacc += __shfl_xor(vacc, 4, 64);
        if (vh == 0) vs_g[row0 + vr] = vacc;
    }
}

// ---------------------------------------------------------------------------
// Kernel C: flash-style attention row-sums, 8 waves/block.
// ROUND-11 SINGLE CHANGE vs round 10: __launch_bounds__(512,2) -- R10's
// (512,4) imposed a 128-VGPR cap; allocator landed at 64 VGPR and spilled
// (signature: WRITE_SIZE 258 MB, FETCH 196 MB, 153 us). With the 256-VGPR
// cap the body (~100-120 VGPR) allocates cleanly; LDS 68 KB -> 2 blocks/CU
// x 8 waves = 16 waves/CU = 4 waves/SIMD if VGPR lands <=128. This is the
// clean test of the issue-latency theory for attn.
// grid 512 = 64 q-blocks x 8 t-chunks. p = exp2(S) since Q pre-scaled.
// ---------------------------------------------------------------------------
__global__ __launch_bounds__(512, 2) void k_attn(
        const __hip_bfloat16* __restrict__ Qb, const __hip_bfloat16* __restrict__ Kb,
        const float* __restrict__ vs_g,
        float* __restrict__ num_g, float* __restrict__ den_g) {
    __shared__ alignas(16) __hip_bfloat16 sK[2][128 * 128];  // 2 x 32 KB, swizzled
    __shared__ float sVS[1024];

    int bid = blockIdx.x;
    int qb = bid >> 3, tc = bid & 7;
    int q0 = qb * 128, t0 = tc * 1024;

    int t = threadIdx.x;
    int wave = t >> 6, lane = t & 63;
    int wr = wave >> 1, wc = wave & 1;   // wr in [0,4): 32-q-row group; wc: t-col half
    int m = lane & 15, quad = lane >> 4;

    bf16x8 qf[4][2];
    #pragma unroll
    for (int i = 0; i < 2; ++i)
        #pragma unroll
        for (int kk = 0; kk < 4; ++kk)
            qf[kk][i] = load_bf8(Qb + (size_t)(q0 + wr * 32 + i * 16 + m) * 128 + kk * 32 + quad * 8);

    #pragma unroll
    for (int p = 0; p < 2; ++p) sVS[p * 512 + t] = vs_g[t0 + p * 512 + t];

    // DMA source mapping: tile = 128 rows x 16 chunks (16B), 2048 slots over
    // 512 threads. Slot s = p*512+t; r = s>>4, pos = s&15; chunk c = pos^(r&15).
    const __hip_bfloat16* gsrc[4];
    #pragma unroll
    for (int p = 0; p < 4; ++p) {
        int s = p * 512 + t;
        int r = s >> 4, pos = s & 15;
        int c = pos ^ (r & 15);
        gsrc[p] = Kb + (size_t)(t0 + r) * 128 + c * 8;
    }
    auto dma_tile = [&](int buf, int it) {
        #pragma unroll
        for (int p = 0; p < 4; ++p)
            dma16(gsrc[p] + (size_t)it * (128 * 128), &sK[buf][(p * 512 + wave * 64) * 8]);
    };

    float num_acc[2][4], den_acc[2][4];
    #pragma unroll
    for (int i = 0; i < 2; ++i)
        #pragma unroll
        for (int r = 0; r < 4; ++r) { num_acc[i][r] = 0.f; den_acc[i][r] = 0.f; }

    dma_tile(0, 0);

    for (int it = 0; it < 8; ++it) {
        __syncthreads();            // drains DMA tile it (+sVS on it=0); frees buf (it+1)&1
        if (it < 7) dma_tile((it + 1) & 1, it + 1);
        const __hip_bfloat16* K = sK[it & 1];

        #pragma unroll
        for (int j = 0; j < 4; ++j) {
            int row = wc * 64 + j * 16 + m;
            bf16x8 bfr[4];
            #pragma unroll
            for (int kk = 0; kk < 4; ++kk)
                bfr[kk] = load_bf8(&K[(size_t)row * 128 + (((kk * 4 + quad) ^ m) * 8)]);

            floatx4 acc[2];
            acc[0] = {0.f, 0.f, 0.f, 0.f};
            acc[1] = {0.f, 0.f, 0.f, 0.f};

            __builtin_amdgcn_s_setprio(1);
            #pragma unroll
            for (int kk = 0; kk < 4; ++kk)
                #pragma unroll
                for (int i = 0; i < 2; ++i)
                    acc[i] = __builtin_amdgcn_mfma_f32_16x16x32_bf16(qf[kk][i], bfr[kk], acc[i], 0, 0, 0);
            __builtin_amdgcn_s_setprio(0);

            float vsv = sVS[it * 128 + row];
            #pragma unroll
            for (int i = 0; i < 2; ++i)
                #pragma unroll
                for (int r = 0; r < 4; ++r) {
                    float p = __builtin_amdgcn_exp2f(acc[i][r]);
                    den_acc[i][r] += p;
                    num_acc[i][r] += p * vsv;
                }
        }
    }

    #pragma unroll
    for (int i = 0; i < 2; ++i)
        #pragma unroll
        for (int r = 0; r < 4; ++r) {
            float n = num_acc[i][r], d = den_acc[i][r];
            #pragma unroll
            for (int mask = 1; mask <= 8; mask <<= 1) {
                n += __shfl_xor(n, mask, 64);
                d += __shfl_xor(d, mask, 64);
            }
            if ((lane & 15) == 0) {
                int row = q0 + wr * 32 + i * 16 + quad * 4 + r;
                atomicAdd(&num_g[row], n);
                atomicAdd(&den_g[row], d);
            }
        }
}

// ---------------------------------------------------------------------------
// Kernel D: gated = x1 * (1 - num/den). float4 grid-mapped, memory-bound.
// (byte-identical to round-9 anchor)
// ---------------------------------------------------------------------------
__global__ void k_final(const float* __restrict__ x1,
                        const float* __restrict__ num_g,
                        const float* __restrict__ den_g,
                        float* __restrict__ outp) {
    int idx = blockIdx.x * 256 + threadIdx.x;  // float4 index, 192 per row
    int s = idx / 192;
    float4 v = *(const float4*)(x1 + (size_t)idx * 4);
    float g = 1.0f - num_g[s] / den_g[s];
    float4 rv;
    rv.x = v.x * g; rv.y = v.y * g; rv.z = v.z * g; rv.w = v.w * g;
    *(float4*)(outp + (size_t)idx * 4) = rv;
}

// ---------------------------------------------------------------------------
extern "C" void kernel_launch(void* const* d_in, const int* in_sizes, int n_in,
                              void* d_out, int out_size, void* d_ws, size_t ws_size,
                              hipStream_t stream) {
    const float* x1  = (const float*)d_in[0];
    const float* x2  = (const float*)d_in[1];
    const float* w_q = (const float*)d_in[2];
    const float* w_k = (const float*)d_in[3];
    const float* w_v = (const float*)d_in[4];
    const float* w_o = (const float*)d_in[5];
    float* outp = (float*)d_out;

    char* ws = (char*)d_ws;
    __hip_bfloat16* wq_bf = (__hip_bfloat16*)(ws + 0);        // 196608 B
    __hip_bfloat16* wk_bf = (__hip_bfloat16*)(ws + 196608);   // 196608 B
    float* c_buf          = (float*)(ws + 393216);            // 3072 B
    __hip_bfloat16* Qb    = (__hip_bfloat16*)(ws + 396288);   // 2 MB
    __hip_bfloat16* Kb    = (__hip_bfloat16*)(ws + 2493440);  // 2 MB
    float* vs_g           = (float*)(ws + 4590592);           // 32 KB
    float* num_g          = (float*)(ws + 4623360);           // 32 KB
    float* den_g          = (float*)(ws + 4656128);           // 32 KB (contig after num_g)

    k_prep<<<132, 256, 0, stream>>>(w_q, w_k, w_v, w_o, wq_bf, wk_bf, c_buf, num_g);
    k_qk<<<512, 256, 0, stream>>>(x1, x2, wq_bf, wk_bf, c_buf, Qb, Kb, vs_g);
    k_attn<<<512, 512, 0, stream>>>(Qb, Kb, vs_g, num_g, den_g);
    k_final<<<6144, 256, 0, stream>>>(x1, num_g, den_g, outp);
}

// Round 12
// 145.527 us; speedup vs baseline: 1.8989x; 1.1628x over previous
//
#include <hip/hip_runtime.h>
#include <hip/hip_bf16.h>
#include <stdint.h>

// exp(s/sqrt(128)) = exp2(s * log2(e)/sqrt(128)); folded into Q at k_qk epilogue
#define SCALE_LOG2E 0.12751743f

typedef __bf16 bf16x8 __attribute__((ext_vector_type(8)));
typedef float floatx4 __attribute__((ext_vector_type(4)));
typedef uint32_t u32x4v __attribute__((ext_vector_type(4)));

__device__ __forceinline__ bf16x8 load_bf8(const void* p) {
    u32x4v v = *(const u32x4v*)p;
    return __builtin_bit_cast(bf16x8, v);
}

__device__ __forceinline__ bf16x8 cvt8(float4 u, float4 v) {
    union { bf16x8 v8; __hip_bfloat16 h[8]; } r;
    r.h[0] = __float2bfloat16(u.x); r.h[1] = __float2bfloat16(u.y);
    r.h[2] = __float2bfloat16(u.z); r.h[3] = __float2bfloat16(u.w);
    r.h[4] = __float2bfloat16(v.x); r.h[5] = __float2bfloat16(v.y);
    r.h[6] = __float2bfloat16(v.z); r.h[7] = __float2bfloat16(v.w);
    return r.v8;
}

// async 16B global -> LDS DMA (no VGPR destination; compiler cannot collapse)
__device__ __forceinline__ void dma16(const void* g, void* l) {
    __builtin_amdgcn_global_load_lds(
        (const __attribute__((address_space(1))) uint32_t*)g,
        (__attribute__((address_space(3))) uint32_t*)l, 16, 0, 0);
}

// ---------------------------------------------------------------------------
// Kernel A: cvt w_q,w_k -> bf16 (b<96); c[768] = w_o @ w_v (b 96..98);
// zero num/den (b 99..131; num_g/den_g contiguous 16384 floats in ws).
// ---------------------------------------------------------------------------
__global__ void k_prep(const float* __restrict__ w_q, const float* __restrict__ w_k,
                       const float* __restrict__ w_v, const float* __restrict__ w_o,
                       __hip_bfloat16* __restrict__ wq_bf,
                       __hip_bfloat16* __restrict__ wk_bf,
                       float* __restrict__ c_out,
                       float* __restrict__ numden) {
    int b = blockIdx.x;
    int t = threadIdx.x;
    if (b < 96) {
        #pragma unroll
        for (int p = 0; p < 8; ++p) {
            int i = b * 2048 + p * 256 + t;
            if (i < 98304) wq_bf[i] = __float2bfloat16(w_q[i]);
            else           wk_bf[i - 98304] = __float2bfloat16(w_k[i - 98304]);
        }
    } else if (b < 99) {
        int j = (b - 96) * 256 + t;
        float acc = 0.f;
        #pragma unroll 8
        for (int k = 0; k < 64; ++k) acc += w_o[k] * w_v[k * 768 + j];
        c_out[j] = acc;
    } else {
        int z = (b - 99) * 512 + t * 2;
        if (z < 16384) { numden[z] = 0.f; numden[z + 1] = 0.f; }
    }
}

// ---------------------------------------------------------------------------
// Kernel B: Q = x1 @ w_q^T * SCALE (bid 0..255), K = x2 @ w_k^T (256..511).
// vs = x2 . c FUSED into the K blocks: each iteration's staged f32 tile is
// dotted against the matching 128-float slice of c (saves a full 25 MB HBM
// re-read of x2). m97-style: block = 32 rows x 128 cols, BK=128, 6 K-iters,
// A-tile double-buffered via global_load_lds width=16 (async DMA), B-frags
// direct from L2-resident bf16 weights, A chunks XOR-swizzled (c^(r&7)) at
// the global source so ds_read_b128 fragment reads are bank-conflict-free.
// (the session's best-measured artifact: 146.4 us total)
// ---------------------------------------------------------------------------
__global__ __launch_bounds__(256, 4) void k_qk(
        const float* __restrict__ x1, const float* __restrict__ x2,
        const __hip_bfloat16* __restrict__ wq_bf,
        const __hip_bfloat16* __restrict__ wk_bf,
        const float* __restrict__ c_in,
        __hip_bfloat16* __restrict__ Qb, __hip_bfloat16* __restrict__ Kb,
        float* __restrict__ vs_g) {
    __shared__ alignas(16) float sA[2][32 * 128];  // 2 x 16 KB, swizzled 16B chunks

    int bid = blockIdx.x;
    int t = threadIdx.x;

    bool isK = bid >= 256;
    int row0 = (bid & 255) * 32;
    const float* x = isK ? x2 : x1;
    const __hip_bfloat16* w = isK ? wk_bf : wq_bf;
    __hip_bfloat16* outp = isK ? Kb : Qb;

    int wave = t >> 6, lane = t & 63;
    int m = lane & 15, quad = lane >> 4;
    int col0 = wave * 32;

    // Per-thread DMA source mapping (constant across iters, only kc changes).
    // Tile = 32 rows x 32 chunks (16B). Slot s = wave*256 + p*64 + lane.
    // r = s>>5, pos = s&31; global chunk stored at pos is c = pos ^ (r&7).
    const float* gsrc[4];
    #pragma unroll
    for (int p = 0; p < 4; ++p) {
        int s = wave * 256 + p * 64 + lane;
        int r = s >> 5, pos = s & 31;
        int c = pos ^ (r & 7);
        gsrc[p] = x + (size_t)(row0 + r) * 768 + c * 4;
    }
    // wave-uniform LDS bases for the 4 DMA instructions (HW adds lane*16)
    auto dma_tile = [&](int buf, int kc) {
        #pragma unroll
        for (int p = 0; p < 4; ++p)
            dma16(gsrc[p] + kc, &sA[buf][(wave * 256 + p * 64) * 4]);
    };

    const __hip_bfloat16* bp = w + (size_t)(col0 + m) * 768 + quad * 8;

    floatx4 acc[2][2];
    #pragma unroll
    for (int i = 0; i < 2; ++i)
        #pragma unroll
        for (int j = 0; j < 2; ++j) acc[i][j] = {0.f, 0.f, 0.f, 0.f};

    // fused-vs state (K blocks): thread owns row vr, 16B chunks vh*4..vh*4+3
    float vacc = 0.f;
    int vr = t >> 3, vh = t & 7;

    dma_tile(0, 0);

    for (int it = 0; it < 6; ++it) {
        __syncthreads();            // drains all DMAs (incl. tile it); frees buf (it+1)&1
        if (it < 5) dma_tile((it + 1) & 1, (it + 1) * 128);

        const float* A = sA[it & 1];
        int kc = it * 128;
        #pragma unroll
        for (int ks = 0; ks < 4; ++ks) {
            bf16x8 afr[2], bfr[2];
            #pragma unroll
            for (int i = 0; i < 2; ++i) {
                int r = i * 16 + m;
                int cb = ks * 8 + quad * 2;
                int p0 = cb ^ (r & 7), p1 = (cb + 1) ^ (r & 7);
                float4 f0 = *(const float4*)&A[r * 128 + p0 * 4];
                float4 f1 = *(const float4*)&A[r * 128 + p1 * 4];
                afr[i] = cvt8(f0, f1);
            }
            #pragma unroll
            for (int j = 0; j < 2; ++j)
                bfr[j] = load_bf8(bp + (size_t)j * 16 * 768 + kc + ks * 32);
            #pragma unroll
            for (int i = 0; i < 2; ++i)
                #pragma unroll
                for (int j = 0; j < 2; ++j)
                    acc[i][j] = __builtin_amdgcn_mfma_f32_16x16x32_bf16(afr[i], bfr[j], acc[i][j], 0, 0, 0);
        }
        if (isK) {
            // vs partial from the staged tile (reads finish before buf reuse:
            // they precede the barrier of it+1). Swizzled chunk pos = c^(vr&7).
            #pragma unroll
            for (int cc = 0; cc < 4; ++cc) {
                int c = vh * 4 + cc;
                int pos = c ^ (vr & 7);
                float4 av = *(const float4*)&A[vr * 128 + pos * 4];
                float4 cv = *(const float4*)&c_in[kc + c * 4];
                vacc += av.x * cv.x + av.y * cv.y + av.z * cv.z + av.w * cv.w;
            }
        }
    }

    // write C (bf16); Q side pre-scaled. C layout: col=lane&15, row=quad*4+reg
    float cscale = isK ? 1.0f : SCALE_LOG2E;
    #pragma unroll
    for (int i = 0; i < 2; ++i)
        #pragma unroll
        for (int j = 0; j < 2; ++j)
            #pragma unroll
            for (int r = 0; r < 4; ++r) {
                int row = row0 + i * 16 + quad * 4 + r;
                int col = col0 + j * 16 + m;
                outp[(size_t)row * 128 + col] = __float2bfloat16(acc[i][j][r] * cscale);
            }

    if (isK) {
        // reduce vs over the 8 vh lanes (adjacent within wave) and store
        vacc += __shfl_xor(vacc, 1, 64);
        vacc += __shfl_xor(vacc, 2, 64);
        vacc += __shfl_xor(vacc, 4, 64);
        if (vh == 0) vs_g[row0 + vr] = vacc;
    }
}

// ---------------------------------------------------------------------------
// Kernel C: flash-style attention row-sums. Q-fragments in registers;
// K tile staged by global_load_lds DMA (double-buffered, ONE barrier/iter)
// with XOR-swizzle pos = c ^ (row&15) applied at the global source (linear
// DMA dest + inverse-swz source + swz read). j-outer MFMA clusters: each
// 16-MFMA cluster is followed by its own exp2/accumulate epilogue so the
// compiler overlaps epilogue(j) with MFMA(j+1); setprio(1) wraps the MFMA
// cluster. grid 512 = 64 q-blocks x 8 t-chunks. p = exp2(S), Q pre-scaled.
// 4 waves x 64 q-rows: 8-wave variants spill (R10: 64 VGPR / 258 MB scratch;
// R11: 128 VGPR / 60 MB scratch) -- this body needs >128 VGPR live, so
// 2 waves/SIMD no-spill is the optimum for this structure.
// ---------------------------------------------------------------------------
__global__ __launch_bounds__(256, 2) void k_attn(
        const __hip_bfloat16* __restrict__ Qb, const __hip_bfloat16* __restrict__ Kb,
        const float* __restrict__ vs_g,
        float* __restrict__ num_g, float* __restrict__ den_g) {
    __shared__ alignas(16) __hip_bfloat16 sK[2][128 * 128];  // 2 x 32 KB, swizzled
    __shared__ float sVS[1024];

    int bid = blockIdx.x;
    int qb = bid >> 3, tc = bid & 7;
    int q0 = qb * 128, t0 = tc * 1024;

    int t = threadIdx.x;
    int wave = t >> 6, lane = t & 63;
    int wr = wave >> 1, wc = wave & 1;
    int m = lane & 15, quad = lane >> 4;

    bf16x8 qf[4][4];
    #pragma unroll
    for (int i = 0; i < 4; ++i)
        #pragma unroll
        for (int kk = 0; kk < 4; ++kk)
            qf[kk][i] = load_bf8(Qb + (size_t)(q0 + wr * 64 + i * 16 + m) * 128 + kk * 32 + quad * 8);

    #pragma unroll
    for (int p = 0; p < 4; ++p) sVS[p * 256 + t] = vs_g[t0 + p * 256 + t];

    // DMA source mapping: tile = 128 rows x 16 chunks (16B). Slot s = p*256+t;
    // r = s>>4, pos = s&15; global chunk at pos is c = pos ^ (r&15).
    const __hip_bfloat16* gsrc[8];
    #pragma unroll
    for (int p = 0; p < 8; ++p) {
        int s = p * 256 + t;
        int r = s >> 4, pos = s & 15;
        int c = pos ^ (r & 15);
        gsrc[p] = Kb + (size_t)(t0 + r) * 128 + c * 8;
    }
    auto dma_tile = [&](int buf, int it) {
        #pragma unroll
        for (int p = 0; p < 8; ++p)
            dma16(gsrc[p] + (size_t)it * (128 * 128), &sK[buf][(p * 256 + wave * 64) * 8]);
    };

    float num_acc[4][4], den_acc[4][4];
    #pragma unroll
    for (int i = 0; i < 4; ++i)
        #pragma unroll
        for (int r = 0; r < 4; ++r) { num_acc[i][r] = 0.f; den_acc[i][r] = 0.f; }

    dma_tile(0, 0);

    for (int it = 0; it < 8; ++it) {
        __syncthreads();            // drains DMA tile it (+sVS on it=0); frees buf (it+1)&1
        if (it < 7) dma_tile((it + 1) & 1, it + 1);
        const __hip_bfloat16* K = sK[it & 1];

        #pragma unroll
        for (int j = 0; j < 4; ++j) {
            int row = wc * 64 + j * 16 + m;
            bf16x8 bfr[4];
            #pragma unroll
            for (int kk = 0; kk < 4; ++kk)
                bfr[kk] = load_bf8(&K[(size_t)row * 128 + (((kk * 4 + quad) ^ m) * 8)]);

            floatx4 acc[4];
            #pragma unroll
            for (int i = 0; i < 4; ++i) acc[i] = {0.f, 0.f, 0.f, 0.f};

            __builtin_amdgcn_s_setprio(1);
            #pragma unroll
            for (int kk = 0; kk < 4; ++kk)
                #pragma unroll
                for (int i = 0; i < 4; ++i)
                    acc[i] = __builtin_amdgcn_mfma_f32_16x16x32_bf16(qf[kk][i], bfr[kk], acc[i], 0, 0, 0);
            __builtin_amdgcn_s_setprio(0);

            float vsv = sVS[it * 128 + row];
            #pragma unroll
            for (int i = 0; i < 4; ++i)
                #pragma unroll
                for (int r = 0; r < 4; ++r) {
                    float p = __builtin_amdgcn_exp2f(acc[i][r]);
                    den_acc[i][r] += p;
                    num_acc[i][r] += p * vsv;
                }
        }
    }

    #pragma unroll
    for (int i = 0; i < 4; ++i)
        #pragma unroll
        for (int r = 0; r < 4; ++r) {
            float n = num_acc[i][r], d = den_acc[i][r];
            #pragma unroll
            for (int mask = 1; mask <= 8; mask <<= 1) {
                n += __shfl_xor(n, mask, 64);
                d += __shfl_xor(d, mask, 64);
            }
            if ((lane & 15) == 0) {
                int row = q0 + wr * 64 + i * 16 + quad * 4 + r;
                atomicAdd(&num_g[row], n);
                atomicAdd(&den_g[row], d);
            }
        }
}

// ---------------------------------------------------------------------------
// Kernel D: gated = x1 * (1 - num/den). float4 grid-mapped, memory-bound.
// ---------------------------------------------------------------------------
__global__ void k_final(const float* __restrict__ x1,
                        const float* __restrict__ num_g,
                        const float* __restrict__ den_g,
                        float* __restrict__ outp) {
    int idx = blockIdx.x * 256 + threadIdx.x;  // float4 index, 192 per row
    int s = idx / 192;
    float4 v = *(const float4*)(x1 + (size_t)idx * 4);
    float g = 1.0f - num_g[s] / den_g[s];
    float4 rv;
    rv.x = v.x * g; rv.y = v.y * g; rv.z = v.z * g; rv.w = v.w * g;
    *(float4*)(outp + (size_t)idx * 4) = rv;
}

// ---------------------------------------------------------------------------
extern "C" void kernel_launch(void* const* d_in, const int* in_sizes, int n_in,
                              void* d_out, int out_size, void* d_ws, size_t ws_size,
                              hipStream_t stream) {
    const float* x1  = (const float*)d_in[0];
    const float* x2  = (const float*)d_in[1];
    const float* w_q = (const float*)d_in[2];
    const float* w_k = (const float*)d_in[3];
    const float* w_v = (const float*)d_in[4];
    const float* w_o = (const float*)d_in[5];
    float* outp = (float*)d_out;

    char* ws = (char*)d_ws;
    __hip_bfloat16* wq_bf = (__hip_bfloat16*)(ws + 0);        // 196608 B
    __hip_bfloat16* wk_bf = (__hip_bfloat16*)(ws + 196608);   // 196608 B
    float* c_buf          = (float*)(ws + 393216);            // 3072 B
    __hip_bfloat16* Qb    = (__hip_bfloat16*)(ws + 396288);   // 2 MB
    __hip_bfloat16* Kb    = (__hip_bfloat16*)(ws + 2493440);  // 2 MB
    float* vs_g           = (float*)(ws + 4590592);           // 32 KB
    float* num_g          = (float*)(ws + 4623360);           // 32 KB
    float* den_g          = (float*)(ws + 4656128);           // 32 KB (contig after num_g)

    k_prep<<<132, 256, 0, stream>>>(w_q, w_k, w_v, w_o, wq_bf, wk_bf, c_buf, num_g);
    k_qk<<<512, 256, 0, stream>>>(x1, x2, wq_bf, wk_bf, c_buf, Qb, Kb, vs_g);
    k_attn<<<512, 256, 0, stream>>>(Qb, Kb, vs_g, num_g, den_g);
    k_final<<<6144, 256, 0, stream>>>(x1, num_g, den_g, outp);
}